// Round 3
// baseline (114557.324 us; speedup 1.0000x reference)
//
#include <hip/hip_runtime.h>
#include <math.h>

#define TDEC 400
#define BB   32
#define TENC 512
#define ENCD 512
#define ATTD 128
#define RNN  1024
#define PRE  256
#define NMEL 80
#define LOCK 31

#define MEL_OFF   0
#define GATE_OFF  (BB*TDEC*NMEL)            // 1,024,000
#define ALIGN_OFF (GATE_OFF + BB*TDEC)      // 1,036,800

// ---------------- threefry2x32, PARTITIONABLE scheme (modern JAX default) ----------------
// counter for element i is the 64-bit value i: cipher input (hi=0, lo=i);
// 32-bit random output = y0 ^ y1.  keep <=> uniform<0.5 <=> bit31==0.
__device__ __forceinline__ unsigned rotl32(unsigned x, unsigned d){ return (x<<d)|(x>>(32u-d)); }

__device__ __forceinline__ int tf_keep(unsigned k0, unsigned k1, unsigned i){
  unsigned ks0 = k0, ks1 = k1, ks2 = k0 ^ k1 ^ 0x1BD11BDAu;
  unsigned x0 = 0u + ks0;       // hi(counter) = 0 for i < 2^32
  unsigned x1 = i  + ks1;       // lo(counter) = i
#define RND(r) { x0 += x1; x1 = rotl32(x1,(r)); x1 ^= x0; }
  RND(13) RND(15) RND(26) RND(6)   x0 += ks1; x1 += ks2 + 1u;
  RND(17) RND(29) RND(16) RND(24)  x0 += ks2; x1 += ks0 + 2u;
  RND(13) RND(15) RND(26) RND(6)   x0 += ks0; x1 += ks1 + 3u;
  RND(17) RND(29) RND(16) RND(24)  x0 += ks1; x1 += ks2 + 4u;
  RND(13) RND(15) RND(26) RND(6)   x0 += ks2; x1 += ks0 + 5u;
#undef RND
  unsigned bits = x0 ^ x1;
  return (bits >> 31) == 0u;
}

__device__ __forceinline__ double sigmd(double x){ return 1.0/(1.0+exp(-x)); }

// ---------------- prenet for all 400 steps (parallel), f64 internal ----------------
// p_all layout: [t][j(256)][b(32)], f32 storage
__global__ void k_prenet(const float* __restrict__ din, const float* __restrict__ w1,
                         const float* __restrict__ w2, float* __restrict__ p_all){
  __shared__ float x_sh[16][NMEL];
  __shared__ double p1_sh[16][PRE];   // 32 KB
  int tid = threadIdx.x;
  int r0 = blockIdx.x * 16;          // flat row = t*32 + b ; 16 rows share t
  int t  = r0 / BB;
  int bbase = r0 & 31;               // 0 or 16
  for (int idx = tid; idx < 16*NMEL; idx += 256){
    int rr = idx / NMEL, m = idx % NMEL;
    float v = 0.f;
    if (t > 0) v = din[(size_t)((bbase+rr)*NMEL + m)*TDEC + (t-1)];
    x_sh[rr][m] = v;
  }
  __syncthreads();
  int j = tid;
  double acc[16];
#pragma unroll
  for (int r=0;r<16;++r) acc[r]=0.0;
  for (int m=0;m<NMEL;++m){
    double wv = (double)w1[j*NMEL + m];
#pragma unroll
    for (int r=0;r<16;++r) acc[r] += wv * (double)x_sh[r][m];
  }
#pragma unroll
  for (int r=0;r<16;++r){
    unsigned i = (unsigned)((r0 + r)*PRE + j);
    double v = acc[r] > 0.0 ? acc[r] : 0.0;
    p1_sh[r][j] = tf_keep(0u,42u,i) ? v*2.0 : 0.0;
  }
  __syncthreads();
#pragma unroll
  for (int r=0;r<16;++r) acc[r]=0.0;
  for (int k=0;k<PRE;++k){
    double wv = (double)w2[j*PRE + k];
#pragma unroll
    for (int r=0;r<16;++r) acc[r] += wv * p1_sh[r][k];
  }
#pragma unroll
  for (int r=0;r<16;++r){
    unsigned i = (unsigned)((r0 + r)*PRE + j);
    double v = acc[r] > 0.0 ? acc[r] : 0.0;
    v = tf_keep(0u,43u,i) ? v*2.0 : 0.0;
    p_all[((size_t)t*PRE + j)*BB + (bbase + r)] = (float)v;
  }
}

// ---------------- processed_memory = memory @ att_wm.T  [b][t][a], f64 accum ----------------
__global__ void k_pm(const float* __restrict__ mem, const float* __restrict__ wm,
                     float* __restrict__ pm){
  __shared__ float m_sh[16][ENCD];   // 32 KB
  int tid = threadIdx.x;
  int rowbase = blockIdx.x * 16;     // (b, t0)
  int b = rowbase / TENC;
  int t0 = rowbase % TENC;
  for (int idx = tid; idx < 16*ENCD; idx += 256){
    int rr = idx >> 9, k = idx & 511;
    m_sh[rr][k] = mem[((size_t)(b*TENC + t0 + rr))*ENCD + k];
  }
  __syncthreads();
  int a = tid & 127, rh = tid >> 7;
  double acc[8];
#pragma unroll
  for (int r=0;r<8;++r) acc[r]=0.0;
  for (int k=0;k<ENCD;++k){
    double wv = (double)wm[a*ENCD + k];
#pragma unroll
    for (int r=0;r<8;++r) acc[r] += wv * (double)m_sh[rh*8+r][k];
  }
#pragma unroll
  for (int r=0;r<8;++r)
    pm[((size_t)(b*TENC + t0 + rh*8 + r))*ATTD + a] = (float)acc[r];
}

// ---------------- Kf[a][k] = sum_f wloc[a,f] * conv_w[f,0,k], f64 → f32 ----------------
__global__ void k_kf(const float* __restrict__ wloc, const float* __restrict__ convw,
                     float* __restrict__ kf){
  int idx = blockIdx.x*256 + threadIdx.x;
  if (idx < ATTD*LOCK){
    int a = idx / LOCK, k = idx % LOCK;
    double s = 0.0;
#pragma unroll
    for (int f=0; f<32; ++f) s += (double)wloc[a*32+f]*(double)convw[f*LOCK+k];
    kf[idx] = (float)s;
  }
}

// ---------------- e-scores: e[b,tt] = v . tanh(pq + pm + conv(cum_w)), f64 ----------------
// grid 128 = b(32) x chunk(4 of 128 t); block 256
__global__ void k_e(const float* __restrict__ pm, const float* __restrict__ kf,
                    const double* __restrict__ cumw, const float* __restrict__ H2,
                    const float* __restrict__ wq, const float* __restrict__ vw,
                    const float* __restrict__ vb, const unsigned char* __restrict__ maskp,
                    double* __restrict__ ebuf, int t){
  __shared__ float kf_sh[ATTD*LOCK];
  __shared__ double cw_sh[128+30];
  __shared__ double pq_sh[ATTD];
  __shared__ float v_sh[ATTD];
  __shared__ double red[256];
  int tid = threadIdx.x;
  int b = blockIdx.x >> 2, c = blockIdx.x & 3, t0 = c*128;
  for (int i = tid; i < ATTD*LOCK; i += 256) kf_sh[i] = kf[i];
  if (tid < ATTD) v_sh[tid] = vw[tid];
  if (tid < 158){
    int g = t0 + tid - 15;
    cw_sh[tid] = (g >= 0 && g < TENC) ? cumw[b*TENC + g] : 0.0;
  }
  {
    int a = tid & 127, kh = tid >> 7;
    const float* hrow = H2 + (size_t)(t & 1)*BB*RNN + (size_t)b*RNN + kh*512;
    const float* wrow = wq + (size_t)a*RNN + kh*512;
    double s = 0.0;
    for (int k=0;k<512;++k) s += (double)hrow[k]*(double)wrow[k];
    red[tid] = s;
  }
  __syncthreads();
  if (tid < ATTD) pq_sh[tid] = red[tid] + red[tid+128];
  __syncthreads();
  int tt = tid & 127, ah = tid >> 7;
  int tg = t0 + tt;
  const float* pmrow = pm + ((size_t)(b*TENC + tg))*ATTD + ah*64;
  double acc = 0.0;
  for (int aa=0; aa<64; ++aa){
    int a = ah*64 + aa;
    const float* kr = kf_sh + a*LOCK;
    double cv = 0.0;
#pragma unroll
    for (int k=0;k<LOCK;++k) cv += (double)kr[k]*cw_sh[tt+k];
    double s = pq_sh[a] + (double)pmrow[aa] + cv;
    acc += (double)v_sh[a]*tanh(s);
  }
  red[tid] = acc;
  __syncthreads();
  if (ah == 0){
    double e = red[tt] + red[tt+128] + (double)vb[0];
    if (maskp[b*TENC + tg]) e = -1e30;
    ebuf[b*TENC + tg] = e;
  }
}

// ---------------- shared LSTM column-block, f64 accumulation/activations ----------------
// block j owns 4 hidden dims; 256 threads = 32 b x 8 item-groups; 2 items each.
__device__ __forceinline__ void lstm_block_dev(
    int j, int tid,
    const float* __restrict__ xA, int lenA,
    const float* __restrict__ xB, int lenB,
    const float* __restrict__ hIn,
    const float* __restrict__ wih, int wihK,
    const float* __restrict__ whh,
    const float* __restrict__ bih, const float* __restrict__ bhh,
    double* __restrict__ cST, float* __restrict__ hOut, float* __restrict__ hOut2,
    float* X_sh, double* G_sh)
{
  int b = tid & 31, item = tid >> 5;
  int d0 = j*4;
  int it0 = item, it1 = item + 8;
  int dl0 = it0 & 3, g0 = it0 >> 2, dl1 = it1 & 3, g1 = it1 >> 2;
  int r0 = g0*RNN + d0 + dl0, r1 = g1*RNN + d0 + dl1;
  double a0 = 0.0, a1 = 0.0;
  int K = wihK + RNN;
  for (int kb = 0; kb < K; kb += 128){
    __syncthreads();
    const float* src; int off;
    if (kb < lenA){ src = xA; off = kb; }
    else if (kb < lenA + lenB){ src = xB; off = kb - lenA; }
    else { src = hIn; off = kb - wihK; }
    for (int idx = tid; idx < 128*32; idx += 256)
      X_sh[idx] = src[(size_t)off*32 + idx];
    __syncthreads();
    const float* wr0; const float* wr1;
    if (kb < wihK){ wr0 = wih + (size_t)r0*wihK + kb; wr1 = wih + (size_t)r1*wihK + kb; }
    else { wr0 = whh + (size_t)r0*RNN + (kb - wihK); wr1 = whh + (size_t)r1*RNN + (kb - wihK); }
    for (int k = 0; k < 128; ++k){
      double xv = (double)X_sh[k*32 + b];
      a0 += xv * (double)wr0[k];
      a1 += xv * (double)wr1[k];
    }
  }
  G_sh[(g0*4 + dl0)*32 + b] = a0 + (double)bih[r0] + (double)bhh[r0];
  G_sh[(g1*4 + dl1)*32 + b] = a1 + (double)bih[r1] + (double)bhh[r1];
  __syncthreads();
  if (tid < 128){
    int bb2 = tid & 31, dl = tid >> 5;
    double gi = G_sh[(0*4+dl)*32 + bb2];
    double gf = G_sh[(1*4+dl)*32 + bb2];
    double gg = G_sh[(2*4+dl)*32 + bb2];
    double go = G_sh[(3*4+dl)*32 + bb2];
    int ci = (d0 + dl)*32 + bb2;
    double c = cST[ci];
    double cn = sigmd(gf)*c + sigmd(gi)*tanh(gg);
    double hn = sigmd(go)*tanh(cn);
    cST[ci] = cn;
    hOut[ci] = (float)hn;
    if (hOut2) hOut2[(size_t)bb2*RNN + d0 + dl] = (float)hn;
  }
}

// ---------------- mid kernel: softmax+cumw+align+ctx (blocks 0..127) || LSTM2(t-1) (128..383) ----------------
__global__ void k_mid(const float* __restrict__ mem, const double* __restrict__ ebuf,
                      double* __restrict__ cumw, float* __restrict__ ctx_all,
                      float* __restrict__ out_align,
                      const float* __restrict__ HT,
                      const float* __restrict__ wih2, const float* __restrict__ whh2,
                      const float* __restrict__ bih2, const float* __restrict__ bhh2,
                      float* __restrict__ decH, double* __restrict__ decC, int t){
  __shared__ float  sflt[128*32];     // X_sh   (16 KB)
  __shared__ double sdblA[512];       // w_sh / G_sh (4 KB)
  __shared__ double sdblB[512];       // red    (4 KB)
  int tid = threadIdx.x;
  if (blockIdx.x < 128){
    if (t >= TDEC) return;
    int b = blockIdx.x >> 2, dg = blockIdx.x & 3;
    double* w_sh = sdblA;
    double* red  = sdblB;
    double e1 = ebuf[b*TENC + tid], e2 = ebuf[b*TENC + 256 + tid];
    red[tid] = fmax(e1, e2); __syncthreads();
    for (int s=128; s>0; s>>=1){ if (tid<s) red[tid] = fmax(red[tid], red[tid+s]); __syncthreads(); }
    double mx = red[0]; __syncthreads();
    double w1 = exp(e1-mx), w2 = exp(e2-mx);
    red[tid] = w1+w2; __syncthreads();
    for (int s=128; s>0; s>>=1){ if (tid<s) red[tid] += red[tid+s]; __syncthreads(); }
    double inv = 1.0/red[0];
    w1 *= inv; w2 *= inv;
    w_sh[tid] = w1; w_sh[tid+256] = w2;
    if (dg == 0){
      cumw[b*TENC + tid] += w1; cumw[b*TENC + 256 + tid] += w2;
      out_align[(size_t)b*(TDEC*TENC) + (size_t)t*TENC + tid] = (float)w1;
      out_align[(size_t)b*(TDEC*TENC) + (size_t)t*TENC + 256 + tid] = (float)w2;
    }
    __syncthreads();
    int dd = tid & 127, th = tid >> 7;
    int d = dg*128 + dd;
    double acc = 0.0;
    const float* mrow = mem + ((size_t)b*TENC)*ENCD + d;
    for (int tt = th*256; tt < th*256+256; ++tt)
      acc += w_sh[tt] * (double)mrow[(size_t)tt*ENCD];
    red[tid] = acc; __syncthreads();
    if (th == 0)
      ctx_all[((size_t)t*ENCD + d)*BB + b] = (float)(red[tid] + red[tid+128]);
  } else {
    if (t < 1) return;
    float* X_sh = sflt;
    double* G_sh = sdblA;   // 512 doubles
    lstm_block_dev(blockIdx.x - 128, tid,
        HT + (size_t)(t & 1)*BB*RNN, RNN,      // x = att_h_{t-1}  [k][b]
        (const float*)0, 0,
        decH + (size_t)(t-1)*BB*RNN,           // h = dec_h_{t-2} (slot t-1)
        wih2, RNN, whh2, bih2, bhh2,
        decC,
        decH + (size_t)t*BB*RNN,               // writes slot t (= dec_h after step t-1)
        (float*)0,
        X_sh, G_sh);
  }
}

// ---------------- LSTM1 kernel ----------------
__global__ void k_lstm1(const float* __restrict__ p_all, const float* __restrict__ ctx_all,
                        float* __restrict__ HT,
                        const float* __restrict__ wih, const float* __restrict__ whh,
                        const float* __restrict__ bih, const float* __restrict__ bhh,
                        double* __restrict__ attC, float* __restrict__ H2, int t){
  __shared__ float  X_sh[128*32];
  __shared__ double G_sh[512];
  const float* hin = HT + (size_t)(t & 1)*BB*RNN;
  float* hout = HT + (size_t)((t+1) & 1)*BB*RNN;
  lstm_block_dev(blockIdx.x, threadIdx.x,
      p_all + (size_t)t*PRE*BB, PRE,
      ctx_all + (size_t)t*ENCD*BB, ENCD,
      hin, wih, 768, whh, bih, bhh,
      attC, hout, H2 + (size_t)((t+1) & 1)*BB*RNN,
      X_sh, G_sh);
}

// ---------------- batched projection + gate, f64 accum ----------------
__global__ void k_proj(const float* __restrict__ decH, const float* __restrict__ ctx_all,
                       const float* __restrict__ pw, const float* __restrict__ pb,
                       const float* __restrict__ gw, const float* __restrict__ gb,
                       float* __restrict__ out){
  __shared__ float X_sh[256*32];
  int tid = threadIdx.x; int t = blockIdx.x;
  int b = tid & 31, og = tid >> 5;
  double acc[11];
#pragma unroll
  for (int i=0;i<11;++i) acc[i]=0.0;
  for (int kc = 0; kc < 1536; kc += 256){
    __syncthreads();
    const float* src; int off;
    if (kc < 1024){ src = decH + (size_t)(t+1)*BB*RNN; off = kc; }
    else          { src = ctx_all + (size_t)t*ENCD*BB; off = kc - 1024; }
    for (int idx = tid; idx < 256*32; idx += 256) X_sh[idx] = src[(size_t)off*32 + idx];
    __syncthreads();
    for (int oi = 0; oi < 11; ++oi){
      int o = og + oi*8;
      if (o > 80) break;
      const float* wr = (o < 80 ? pw + (size_t)o*1536 : gw) + kc;
      double s = 0.0;
      for (int k=0;k<256;++k) s += (double)X_sh[k*32 + b] * (double)wr[k];
      acc[oi] += s;
    }
  }
  for (int oi = 0; oi < 11; ++oi){
    int o = og + oi*8;
    if (o > 80) break;
    if (o < 80) out[(size_t)b*TDEC*NMEL + (size_t)t*NMEL + o] = (float)(acc[oi] + (double)pb[o]);
    else        out[GATE_OFF + (size_t)b*TDEC + t] = (float)(acc[oi] + (double)gb[0]);
  }
}

extern "C" void kernel_launch(void* const* d_in, const int* in_sizes, int n_in,
                              void* d_out, int out_size, void* d_ws, size_t ws_size,
                              hipStream_t stream) {
  const float* mem   = (const float*)d_in[0];
  const float* din   = (const float*)d_in[1];
  const unsigned char* maskp = (const unsigned char*)d_in[2];
  const float* pw1   = (const float*)d_in[3];
  const float* pw2   = (const float*)d_in[4];
  const float* wq    = (const float*)d_in[5];
  const float* wm    = (const float*)d_in[6];
  const float* convw = (const float*)d_in[7];
  const float* wloc  = (const float*)d_in[8];
  const float* vw    = (const float*)d_in[9];
  const float* vb    = (const float*)d_in[10];
  const float* wih1  = (const float*)d_in[11];
  const float* whh1  = (const float*)d_in[12];
  const float* bih1  = (const float*)d_in[13];
  const float* bhh1  = (const float*)d_in[14];
  const float* wih2  = (const float*)d_in[15];
  const float* whh2  = (const float*)d_in[16];
  const float* bih2  = (const float*)d_in[17];
  const float* bhh2  = (const float*)d_in[18];
  const float* prw   = (const float*)d_in[19];
  const float* prb   = (const float*)d_in[20];
  const float* gw    = (const float*)d_in[21];
  const float* gb    = (const float*)d_in[22];

  float* ws_f = (float*)d_ws;
  float* P_ALL = ws_f;                      // 3,276,800
  float* PM    = P_ALL + 3276800;           // 2,097,152
  float* CTX   = PM + 2097152;              // 6,553,600
  float* DECH  = CTX + 6553600;             // 13,140,992 (401 slots; slot s = dec_h after step s-1)
  float* HT    = DECH + 13140992;           // 2*32768  [slot][k][b]
  float* H2    = HT + 65536;                // 2*32768  [slot][b][k]
  float* KF    = H2 + 65536;                // 4,096
  double* ws_d = (double*)(KF + 4096);      // byte offset 100,814,848 (8-aligned)
  double* ATT_C = ws_d;                     // 32,768
  double* DEC_C = ATT_C + 32768;            // 32,768
  double* CUMW  = DEC_C + 32768;            // 16,384
  double* EBUF  = CUMW + 16384;             // 16,384

  // zero recurrent state (ws is re-poisoned to 0xAA before every timed launch)
  hipMemsetAsync(DECH, 0, (size_t)32768*sizeof(float), stream);     // dec_h slot 0
  hipMemsetAsync(HT, 0, (size_t)131072*sizeof(float), stream);      // HT + H2
  hipMemsetAsync(ATT_C, 0, (size_t)81920*sizeof(double), stream);   // ATT_C, DEC_C, CUMW

  k_prenet<<<800, 256, 0, stream>>>(din, pw1, pw2, P_ALL);
  k_pm<<<1024, 256, 0, stream>>>(mem, wm, PM);
  k_kf<<<16, 256, 0, stream>>>(wloc, convw, KF);

  float* out = (float*)d_out;
  for (int t = 0; t <= TDEC; ++t){
    if (t < TDEC)
      k_e<<<128, 256, 0, stream>>>(PM, KF, CUMW, H2, wq, vw, vb, maskp, EBUF, t);
    k_mid<<<384, 256, 0, stream>>>(mem, EBUF, CUMW, CTX, out + ALIGN_OFF,
                                   HT, wih2, whh2, bih2, bhh2, DECH, DEC_C, t);
    if (t < TDEC)
      k_lstm1<<<256, 256, 0, stream>>>(P_ALL, CTX, HT, wih1, whh1, bih1, bhh1,
                                       ATT_C, H2, t);
  }
  k_proj<<<400, 256, 0, stream>>>(DECH, CTX, prw, prb, gw, gb, out);
}

// Round 5
// 54788.855 us; speedup vs baseline: 2.0909x; 2.0909x over previous
//
#include <hip/hip_runtime.h>
#include <math.h>

#define TDEC 400
#define BB   32
#define TENC 512
#define ENCD 512
#define ATTD 128
#define RNN  1024
#define PRE  256
#define NMEL 80
#define LOCK 31

#define MEL_OFF   0
#define GATE_OFF  (BB*TDEC*NMEL)            // 1,024,000
#define ALIGN_OFF (GATE_OFF + BB*TDEC)      // 1,036,800

// ---------------- threefry2x32, PARTITIONABLE scheme (modern JAX default) ----------------
__device__ __forceinline__ unsigned rotl32(unsigned x, unsigned d){ return (x<<d)|(x>>(32u-d)); }

__device__ __forceinline__ int tf_keep(unsigned k0, unsigned k1, unsigned i){
  unsigned ks0 = k0, ks1 = k1, ks2 = k0 ^ k1 ^ 0x1BD11BDAu;
  unsigned x0 = 0u + ks0;       // hi(counter) = 0 for i < 2^32
  unsigned x1 = i  + ks1;       // lo(counter) = i
#define RND(r) { x0 += x1; x1 = rotl32(x1,(r)); x1 ^= x0; }
  RND(13) RND(15) RND(26) RND(6)   x0 += ks1; x1 += ks2 + 1u;
  RND(17) RND(29) RND(16) RND(24)  x0 += ks2; x1 += ks0 + 2u;
  RND(13) RND(15) RND(26) RND(6)   x0 += ks0; x1 += ks1 + 3u;
  RND(17) RND(29) RND(16) RND(24)  x0 += ks1; x1 += ks2 + 4u;
  RND(13) RND(15) RND(26) RND(6)   x0 += ks2; x1 += ks0 + 5u;
#undef RND
  unsigned bits = x0 ^ x1;
  return (bits >> 31) == 0u;
}

__device__ __forceinline__ float sigmf(float x){ return 1.f/(1.f+expf(-x)); }

// ---------------- prenet for all 400 steps (parallel), f64 internal (one-time) ----------------
// p_all layout: [t][j(256)][b(32)], f32 storage
__global__ void k_prenet(const float* __restrict__ din, const float* __restrict__ w1,
                         const float* __restrict__ w2, float* __restrict__ p_all){
  __shared__ float x_sh[16][NMEL];
  __shared__ double p1_sh[16][PRE];   // 32 KB
  int tid = threadIdx.x;
  int r0 = blockIdx.x * 16;          // flat row = t*32 + b ; 16 rows share t
  int t  = r0 / BB;
  int bbase = r0 & 31;               // 0 or 16
  for (int idx = tid; idx < 16*NMEL; idx += 256){
    int rr = idx / NMEL, m = idx % NMEL;
    float v = 0.f;
    if (t > 0) v = din[(size_t)((bbase+rr)*NMEL + m)*TDEC + (t-1)];
    x_sh[rr][m] = v;
  }
  __syncthreads();
  int j = tid;
  double acc[16];
#pragma unroll
  for (int r=0;r<16;++r) acc[r]=0.0;
  for (int m=0;m<NMEL;++m){
    double wv = (double)w1[j*NMEL + m];
#pragma unroll
    for (int r=0;r<16;++r) acc[r] += wv * (double)x_sh[r][m];
  }
#pragma unroll
  for (int r=0;r<16;++r){
    unsigned i = (unsigned)((r0 + r)*PRE + j);
    double v = acc[r] > 0.0 ? acc[r] : 0.0;
    p1_sh[r][j] = tf_keep(0u,42u,i) ? v*2.0 : 0.0;
  }
  __syncthreads();
#pragma unroll
  for (int r=0;r<16;++r) acc[r]=0.0;
  for (int k=0;k<PRE;++k){
    double wv = (double)w2[j*PRE + k];
#pragma unroll
    for (int r=0;r<16;++r) acc[r] += wv * p1_sh[r][k];
  }
#pragma unroll
  for (int r=0;r<16;++r){
    unsigned i = (unsigned)((r0 + r)*PRE + j);
    double v = acc[r] > 0.0 ? acc[r] : 0.0;
    v = tf_keep(0u,43u,i) ? v*2.0 : 0.0;
    p_all[((size_t)t*PRE + j)*BB + (bbase + r)] = (float)v;
  }
}

// ---------------- processed_memory = memory @ att_wm.T  [b][t][a], f64 accum (one-time) ----------------
__global__ void k_pm(const float* __restrict__ mem, const float* __restrict__ wm,
                     float* __restrict__ pm){
  __shared__ float m_sh[16][ENCD];   // 32 KB
  int tid = threadIdx.x;
  int rowbase = blockIdx.x * 16;     // (b, t0)
  int b = rowbase / TENC;
  int t0 = rowbase % TENC;
  for (int idx = tid; idx < 16*ENCD; idx += 256){
    int rr = idx >> 9, k = idx & 511;
    m_sh[rr][k] = mem[((size_t)(b*TENC + t0 + rr))*ENCD + k];
  }
  __syncthreads();
  int a = tid & 127, rh = tid >> 7;
  double acc[8];
#pragma unroll
  for (int r=0;r<8;++r) acc[r]=0.0;
  for (int k=0;k<ENCD;++k){
    double wv = (double)wm[a*ENCD + k];
#pragma unroll
    for (int r=0;r<8;++r) acc[r] += wv * (double)m_sh[rh*8+r][k];
  }
#pragma unroll
  for (int r=0;r<8;++r)
    pm[((size_t)(b*TENC + t0 + rh*8 + r))*ATTD + a] = (float)acc[r];
}

// ---------------- Kf[a][k] = sum_f wloc[a,f] * conv_w[f,0,k], f64 → f32 (one-time) ----------------
__global__ void k_kf(const float* __restrict__ wloc, const float* __restrict__ convw,
                     float* __restrict__ kf){
  int idx = blockIdx.x*256 + threadIdx.x;
  if (idx < ATTD*LOCK){
    int a = idx / LOCK, k = idx % LOCK;
    double s = 0.0;
#pragma unroll
    for (int f=0; f<32; ++f) s += (double)wloc[a*32+f]*(double)convw[f*LOCK+k];
    kf[idx] = (float)s;
  }
}

// ---------------- e-scores: e[b,tt] = v . tanh(pq + pm + conv(cum_w)), f32, 512 thr ----------------
// grid 128 = b(32) x chunk(4 of 128 enc positions)
__global__ void __launch_bounds__(512)
k_e(const float* __restrict__ pm, const float* __restrict__ kf,
    const float* __restrict__ cumw, const float* __restrict__ H2,
    const float* __restrict__ wq, const float* __restrict__ vw,
    const float* __restrict__ vb, const unsigned char* __restrict__ maskp,
    float* __restrict__ ebuf, int t){
  __shared__ float kf_sh[ATTD*LOCK];   // 3968
  __shared__ float cw_sh[128+30];
  __shared__ float pq_sh[ATTD];
  __shared__ float v_sh[ATTD];
  __shared__ float red[512];
  int tid = threadIdx.x;
  int b = blockIdx.x >> 2, c = blockIdx.x & 3, t0 = c*128;
  for (int i = tid; i < ATTD*LOCK; i += 512) kf_sh[i] = kf[i];
  if (tid < ATTD) v_sh[tid] = vw[tid];
  if (tid < 158){
    int g = t0 + tid - 15;
    cw_sh[tid] = (g >= 0 && g < TENC) ? cumw[b*TENC + g] : 0.f;
  }
  {
    int a = tid & 127, kh = tid >> 7;                 // 4-way split-K over 1024
    const float* hrow = H2 + (size_t)(t & 1)*BB*RNN + (size_t)b*RNN + kh*256;
    const float* wrow = wq + (size_t)a*RNN + kh*256;
    float s = 0.f;
    for (int k=0;k<256;++k) s += hrow[k]*wrow[k];
    red[tid] = s;
  }
  __syncthreads();
  if (tid < ATTD) pq_sh[tid] = red[tid] + red[tid+128] + red[tid+256] + red[tid+384];
  __syncthreads();
  int tt = tid & 127, ah = tid >> 7;                  // 4 a-groups of 32
  int tg = t0 + tt;
  const float* pmrow = pm + ((size_t)(b*TENC + tg))*ATTD + ah*32;
  float acc = 0.f;
  for (int aa=0; aa<32; ++aa){
    int a = ah*32 + aa;
    const float* kr = kf_sh + a*LOCK;
    float cv = 0.f;
#pragma unroll
    for (int k=0;k<LOCK;++k) cv += kr[k]*cw_sh[tt+k];
    float s = pq_sh[a] + pmrow[aa] + cv;
    acc += v_sh[a]*tanhf(s);
  }
  red[tid] = acc;
  __syncthreads();
  if (ah == 0){
    float e = red[tt] + red[tt+128] + red[tt+256] + red[tt+384] + vb[0];
    if (maskp[b*TENC + tg]) e = -1e30f;
    ebuf[b*TENC + tg] = e;
  }
}

// ---------------- shared LSTM column-block, 512 threads, f32 + f64 chunk-accum ----------------
// block j owns 4 hidden dims (16 gate rows); 512 threads = 32 b x 16 rows, 1 row each.
__device__ __forceinline__ void lstm_block_dev(
    int j, int tid,
    const float* __restrict__ xA, int lenA,
    const float* __restrict__ xB, int lenB,
    const float* __restrict__ hIn,
    const float* __restrict__ wih, int wihK,
    const float* __restrict__ whh,
    const float* __restrict__ bih, const float* __restrict__ bhh,
    float* __restrict__ cST, float* __restrict__ hOut, float* __restrict__ hOut2,
    float* X_sh, float* G_sh)
{
  int b = tid & 31, item = tid >> 5;       // item 0..15 = g*4 + dl
  int d0 = j*4;
  int dl = item & 3, g = item >> 2;
  int r = g*RNN + d0 + dl;
  double a_tot = 0.0;
  int K = wihK + RNN;
  for (int kb = 0; kb < K; kb += 128){
    __syncthreads();
    const float* src; int off;
    if (kb < lenA){ src = xA; off = kb; }
    else if (kb < lenA + lenB){ src = xB; off = kb - lenA; }
    else { src = hIn; off = kb - wihK; }
    for (int idx = tid; idx < 128*32; idx += 512)
      X_sh[idx] = src[(size_t)off*32 + idx];
    __syncthreads();
    const float* wr;
    if (kb < wihK) wr = wih + (size_t)r*wihK + kb;
    else           wr = whh + (size_t)r*RNN + (kb - wihK);
    float ac = 0.f;
    for (int k = 0; k < 128; ++k)
      ac += X_sh[k*32 + b] * wr[k];
    a_tot += (double)ac;
  }
  G_sh[item*32 + b] = (float)(a_tot + (double)bih[r] + (double)bhh[r]);
  __syncthreads();
  if (tid < 128){
    int bb2 = tid & 31, dl2 = tid >> 5;
    float gi = G_sh[(0*4+dl2)*32 + bb2];
    float gf = G_sh[(1*4+dl2)*32 + bb2];
    float gg = G_sh[(2*4+dl2)*32 + bb2];
    float go = G_sh[(3*4+dl2)*32 + bb2];
    int ci = (d0 + dl2)*32 + bb2;
    float c = cST[ci];
    float cn = sigmf(gf)*c + sigmf(gi)*tanhf(gg);
    float hn = sigmf(go)*tanhf(cn);
    cST[ci] = cn;
    hOut[ci] = hn;
    if (hOut2) hOut2[(size_t)bb2*RNN + d0 + dl2] = hn;
  }
}

// ---------------- mid kernel: softmax+cumw+align+ctx (0..127) || LSTM2(t-1) (128..383) ----------------
__global__ void __launch_bounds__(512)
k_mid(const float* __restrict__ mem, const float* __restrict__ ebuf,
      float* __restrict__ cumw, float* __restrict__ ctx_all,
      float* __restrict__ out_align,
      const float* __restrict__ HT,
      const float* __restrict__ wih2, const float* __restrict__ whh2,
      const float* __restrict__ bih2, const float* __restrict__ bhh2,
      float* __restrict__ decH, float* __restrict__ decC, int t){
  __shared__ float X_sh[128*32];      // 16 KB (also w_sh/red region owner varies)
  __shared__ float shA[512];          // w_sh  / G_sh
  __shared__ float shB[512];          // red
  int tid = threadIdx.x;
  if (blockIdx.x < 128){
    if (t >= TDEC) return;
    int b = blockIdx.x >> 2, dg = blockIdx.x & 3;
    float* w_sh = shA;
    float* red  = shB;
    float e = ebuf[b*TENC + tid];
    red[tid] = e; __syncthreads();
    for (int s=256; s>0; s>>=1){ if (tid<s) red[tid] = fmaxf(red[tid], red[tid+s]); __syncthreads(); }
    float mx = red[0]; __syncthreads();
    float w = expf(e - mx);
    red[tid] = w; __syncthreads();
    for (int s=256; s>0; s>>=1){ if (tid<s) red[tid] += red[tid+s]; __syncthreads(); }
    float inv = 1.f/red[0];
    w *= inv;
    w_sh[tid] = w;
    if (dg == 0){
      cumw[b*TENC + tid] += w;
      out_align[(size_t)b*(TDEC*TENC) + (size_t)t*TENC + tid] = w;
    }
    __syncthreads();
    int dd = tid & 127, th = tid >> 7;
    int d = dg*128 + dd;
    float acc = 0.f;
    const float* mrow = mem + ((size_t)b*TENC)*ENCD + d;
    for (int tt = th*128; tt < th*128+128; ++tt)
      acc += w_sh[tt] * mrow[(size_t)tt*ENCD];
    red[tid] = acc; __syncthreads();
    if (th == 0)
      ctx_all[((size_t)t*ENCD + d)*BB + b] = red[dd] + red[dd+128] + red[dd+256] + red[dd+384];
  } else {
    if (t < 1) return;
    lstm_block_dev(blockIdx.x - 128, tid,
        HT + (size_t)(t & 1)*BB*RNN, RNN,      // x = att_h_{t-1}  [k][b]
        (const float*)0, 0,
        decH + (size_t)(t-1)*BB*RNN,           // h = dec_h_{t-2} (slot t-1)
        wih2, RNN, whh2, bih2, bhh2,
        decC,
        decH + (size_t)t*BB*RNN,               // writes slot t (= dec_h after step t-1)
        (float*)0,
        X_sh, shA);
  }
}

// ---------------- LSTM1 kernel ----------------
__global__ void __launch_bounds__(512)
k_lstm1(const float* __restrict__ p_all, const float* __restrict__ ctx_all,
        float* __restrict__ HT,
        const float* __restrict__ wih, const float* __restrict__ whh,
        const float* __restrict__ bih, const float* __restrict__ bhh,
        float* __restrict__ attC, float* __restrict__ H2, int t){
  __shared__ float X_sh[128*32];
  __shared__ float G_sh[512];
  const float* hin = HT + (size_t)(t & 1)*BB*RNN;
  float* hout = HT + (size_t)((t+1) & 1)*BB*RNN;
  lstm_block_dev(blockIdx.x, threadIdx.x,
      p_all + (size_t)t*PRE*BB, PRE,
      ctx_all + (size_t)t*ENCD*BB, ENCD,
      hin, wih, 768, whh, bih, bhh,
      attC, hout, H2 + (size_t)((t+1) & 1)*BB*RNN,
      X_sh, G_sh);
}

// ---------------- batched projection + gate, f32 chunks + f64 total ----------------
__global__ void k_proj(const float* __restrict__ decH, const float* __restrict__ ctx_all,
                       const float* __restrict__ pw, const float* __restrict__ pb,
                       const float* __restrict__ gw, const float* __restrict__ gb,
                       float* __restrict__ out){
  __shared__ float X_sh[256*32];
  int tid = threadIdx.x; int t = blockIdx.x;
  int b = tid & 31, og = tid >> 5;
  double acc[11];
#pragma unroll
  for (int i=0;i<11;++i) acc[i]=0.0;
  for (int kc = 0; kc < 1536; kc += 256){
    __syncthreads();
    const float* src; int off;
    if (kc < 1024){ src = decH + (size_t)(t+1)*BB*RNN; off = kc; }
    else          { src = ctx_all + (size_t)t*ENCD*BB; off = kc - 1024; }
    for (int idx = tid; idx < 256*32; idx += 256) X_sh[idx] = src[(size_t)off*32 + idx];
    __syncthreads();
    for (int oi = 0; oi < 11; ++oi){
      int o = og + oi*8;
      if (o > 80) break;
      const float* wr = (o < 80 ? pw + (size_t)o*1536 : gw) + kc;
      float s = 0.f;
      for (int k=0;k<256;++k) s += X_sh[k*32 + b] * wr[k];
      acc[oi] += (double)s;
    }
  }
  for (int oi = 0; oi < 11; ++oi){
    int o = og + oi*8;
    if (o > 80) break;
    if (o < 80) out[(size_t)b*TDEC*NMEL + (size_t)t*NMEL + o] = (float)(acc[oi] + (double)pb[o]);
    else        out[GATE_OFF + (size_t)b*TDEC + t] = (float)(acc[oi] + (double)gb[0]);
  }
}

extern "C" void kernel_launch(void* const* d_in, const int* in_sizes, int n_in,
                              void* d_out, int out_size, void* d_ws, size_t ws_size,
                              hipStream_t stream) {
  const float* mem   = (const float*)d_in[0];
  const float* din   = (const float*)d_in[1];
  const unsigned char* maskp = (const unsigned char*)d_in[2];
  const float* pw1   = (const float*)d_in[3];
  const float* pw2   = (const float*)d_in[4];
  const float* wq    = (const float*)d_in[5];
  const float* wm    = (const float*)d_in[6];
  const float* convw = (const float*)d_in[7];
  const float* wloc  = (const float*)d_in[8];
  const float* vw    = (const float*)d_in[9];
  const float* vb    = (const float*)d_in[10];
  const float* wih1  = (const float*)d_in[11];
  const float* whh1  = (const float*)d_in[12];
  const float* bih1  = (const float*)d_in[13];
  const float* bhh1  = (const float*)d_in[14];
  const float* wih2  = (const float*)d_in[15];
  const float* whh2  = (const float*)d_in[16];
  const float* bih2  = (const float*)d_in[17];
  const float* bhh2  = (const float*)d_in[18];
  const float* prw   = (const float*)d_in[19];
  const float* prb   = (const float*)d_in[20];
  const float* gw    = (const float*)d_in[21];
  const float* gb    = (const float*)d_in[22];

  float* ws_f = (float*)d_ws;
  float* P_ALL = ws_f;                      // 3,276,800
  float* PM    = P_ALL + 3276800;           // 2,097,152
  float* CTX   = PM + 2097152;              // 6,553,600
  float* DECH  = CTX + 6553600;             // 13,140,992 (401 slots; slot s = dec_h after step s-1)
  float* HT    = DECH + 13140992;           // 2*32768  [slot][k][b]
  float* H2    = HT + 65536;                // 2*32768  [slot][b][k]
  float* KF    = H2 + 65536;                // 4,096
  float* ATT_C = KF + 4096;                 // 32,768
  float* DEC_C = ATT_C + 32768;             // 32,768
  float* CUMW  = DEC_C + 32768;             // 16,384
  float* EBUF  = CUMW + 16384;              // 16,384

  // zero recurrent state (ws is re-poisoned to 0xAA before every timed launch)
  hipMemsetAsync(DECH, 0, (size_t)32768*sizeof(float), stream);     // dec_h slot 0
  hipMemsetAsync(HT, 0, (size_t)131072*sizeof(float), stream);      // HT + H2
  hipMemsetAsync(ATT_C, 0, (size_t)81920*sizeof(float), stream);    // ATT_C, DEC_C, CUMW

  k_prenet<<<800, 256, 0, stream>>>(din, pw1, pw2, P_ALL);
  k_pm<<<1024, 256, 0, stream>>>(mem, wm, PM);
  k_kf<<<16, 256, 0, stream>>>(wloc, convw, KF);

  float* out = (float*)d_out;
  for (int t = 0; t <= TDEC; ++t){
    if (t < TDEC)
      k_e<<<128, 512, 0, stream>>>(PM, KF, CUMW, H2, wq, vw, vb, maskp, EBUF, t);
    k_mid<<<384, 512, 0, stream>>>(mem, EBUF, CUMW, CTX, out + ALIGN_OFF,
                                   HT, wih2, whh2, bih2, bhh2, DECH, DEC_C, t);
    if (t < TDEC)
      k_lstm1<<<256, 512, 0, stream>>>(P_ALL, CTX, HT, wih1, whh1, bih1, bhh1,
                                       ATT_C, H2, t);
  }
  k_proj<<<400, 256, 0, stream>>>(DECH, CTX, prw, prb, gw, gb, out);
}